// Round 5
// baseline (194.570 us; speedup 1.0000x reference)
//
#include <hip/hip_runtime.h>

#define N_RAYS 65536
#define N_PTS  128
#define FAR_DELTA 1e10f

#define BLOCK   256
#define NBLOCKS 1024                          // 4 blocks/CU, all resident (40 KB LDS)
#define NWAVES  (NBLOCKS * (BLOCK / 64))      // 4096 waves
#define NPAIRS  (N_RAYS / 2)
#define NP      (NPAIRS / NWAVES)             // 8 pairs per wave

// DPP cross-lane on the VALU pipe (frees the per-CU LDS/DS pipe, which the
// round-4 profile fingered as the limiter: ~1200 cy/pair of dependent
// ds_bpermute chains == the whole 64 us).
#define ROW_SHR(n)  (0x110 | (n))
#define ROW_SHL(n)  (0x100 | (n))
#define ROW_BCAST15 0x142

template<int CTRL, int RMASK, bool BC>
__device__ __forceinline__ float dpp_f(float x) {
    return __builtin_bit_cast(float,
        __builtin_amdgcn_update_dpp(0, __builtin_bit_cast(int, x),
                                    CTRL, RMASK, 0xF, BC));
}

__global__ __launch_bounds__(BLOCK) void volrend_kernel(
    const float* __restrict__ depth,
    const float* __restrict__ density,
    const float* __restrict__ feature,
    float* __restrict__ out)
{
    __shared__ float4 sbuf[4][2][5 * 64];     // [wave][buf][slot*64] = 40 KB

    const int tid  = threadIdx.x;
    const int w    = tid >> 6;
    const int lane = tid & 63;
    const int sl   = lane & 31;
    const int g    = (int)blockIdx.x * (BLOCK / 64) + w;

#define GLD(gp_, lp_)                                                         \
    __builtin_amdgcn_global_load_lds(                                         \
        (const __attribute__((address_space(1))) void*)(gp_),                 \
        (__attribute__((address_space(3))) void*)(lp_), 16, 0, 0)

#define ISSUE(p_, b_)                                                         \
    do {                                                                      \
        float4* wb_ = &sbuf[w][b_][0];                                        \
        GLD(depth   + (size_t)(p_) * 256 + 4 * lane, wb_);                    \
        GLD(density + (size_t)(p_) * 256 + 4 * lane, wb_ + 64);               \
        const float* fp_ = feature + (size_t)(p_) * 768 + 4 * lane;           \
        GLD(fp_,       wb_ + 128);                                            \
        GLD(fp_ + 256, wb_ + 192);                                            \
        GLD(fp_ + 512, wb_ + 256);                                            \
    } while (0)

    ISSUE(g, 0);
    ISSUE(NWAVES + g, 1);

#pragma unroll
    for (int p = 0; p < NP; ++p) {
        // vmcnt ledger identical to round 4 (same VMEM ops, verified passing):
        if      (p == 0)      asm volatile("s_waitcnt vmcnt(5)" ::: "memory");
        else if (p == 1)      asm volatile("s_waitcnt vmcnt(6)" ::: "memory");
        else if (p < NP - 1)  asm volatile("s_waitcnt vmcnt(7)" ::: "memory");
        else                  asm volatile("s_waitcnt vmcnt(2)" ::: "memory");

        const float4* wb   = &sbuf[w][p & 1][0];
        const float*  ldsf = (const float*)wb;
        float4 d   = wb[lane];
        float4 rho = wb[64 + lane];
        float4 f0  = wb[128 + 3 * lane];
        float4 f1  = wb[129 + 3 * lane];
        float4 f2  = wb[130 + 3 * lane];
        // next lane's first depth, from LDS (replaces shfl_down). Lane 63
        // reads the density slot's first float -- unused (sl==31 -> sentinel).
        float  nx  = ldsf[4 * lane + 4];

        asm volatile("s_waitcnt lgkmcnt(0)" ::: "memory");
        if (p + 2 < NP) ISSUE((p + 2) * NWAVES + g, p & 1);

        // ---- taus + in-register local prefix ----
        float t0 = rho.x * (d.y - d.x);
        float t1 = rho.y * (d.z - d.y);
        float t2 = rho.z * (d.w - d.z);
        float t3 = rho.w * ((sl == 31) ? FAR_DELTA : (nx - d.w));
        float q1 = t0, q2 = q1 + t1, q3 = q2 + t2, tot = q3 + t3;

        // ---- 32-lane segmented exclusive scan, pure DPP (VALU pipe) ----
        // Row-inclusive scan (16-lane Hillis-Steele, 0-fill at row edges):
        float incl = tot;
        incl += dpp_f<ROW_SHR(1), 0xF, true>(incl);
        incl += dpp_f<ROW_SHR(2), 0xF, true>(incl);
        incl += dpp_f<ROW_SHR(4), 0xF, true>(incl);
        incl += dpp_f<ROW_SHR(8), 0xF, true>(incl);
        // Exclusive via shift (NOT incl-tot: avoids sentinel cancellation):
        float e = dpp_f<ROW_SHR(1), 0xF, true>(incl);
        // Add previous row's total into rows 1 and 3 only (row_mask=0xA).
        // Lane31's sentinel-poisoned incl broadcasts to row 2 but is masked
        // off, so segment 1 restarts at 0 and no huge value enters any sum.
        e += dpp_f<ROW_BCAST15, 0xA, false>(incl);

        float T0 = __expf(-e);
        float T1 = __expf(-(e + q1));
        float T2 = __expf(-(e + q2));
        float T3 = __expf(-(e + q3));
        float T4 = __expf(-(e + tot));        // sl==31: exp(-1e10*rho) -> 0
        float w0 = T0 - T1, w1 = T1 - T2, w2 = T2 - T3, w3 = T3 - T4;

        float a3 = w0 * d.x  + w1 * d.y  + w2 * d.z  + w3 * d.w;
        float a0 = w0 * f0.x + w1 * f0.w + w2 * f1.z + w3 * f2.y;
        float a1 = w0 * f0.y + w1 * f1.x + w2 * f1.w + w3 * f2.z;
        float a2 = w0 * f0.z + w1 * f1.y + w2 * f2.x + w3 * f2.w;

        // ---- segment reduction: DPP row tree + one ds_swizzle xor:16 ----
        // After the 4 shl steps, row-local lane 0 holds the row sum; the
        // single swizzle adds the partner row's sum (lane0<->16, 32<->48).
#define RED(a_)                                                               \
    do {                                                                      \
        a_ += dpp_f<ROW_SHL(8), 0xF, true>(a_);                               \
        a_ += dpp_f<ROW_SHL(4), 0xF, true>(a_);                               \
        a_ += dpp_f<ROW_SHL(2), 0xF, true>(a_);                               \
        a_ += dpp_f<ROW_SHL(1), 0xF, true>(a_);                               \
        a_ += __builtin_bit_cast(float,                                       \
            __builtin_amdgcn_ds_swizzle(__builtin_bit_cast(int, a_), 0x401F));\
    } while (0)
        RED(a0); RED(a1); RED(a2); RED(a3);
#undef RED

        if (sl == 0) {
            int ray = 2 * (p * NWAVES + g) + (lane >> 5);
            *(float4*)(out + (size_t)ray * 4) = make_float4(a0, a1, a2, a3);
        }
    }
#undef ISSUE
#undef GLD
}

extern "C" void kernel_launch(void* const* d_in, const int* in_sizes, int n_in,
                              void* d_out, int out_size, void* d_ws, size_t ws_size,
                              hipStream_t stream) {
    const float* depth   = (const float*)d_in[0];
    const float* density = (const float*)d_in[1];
    const float* feature = (const float*)d_in[2];
    float* out = (float*)d_out;

    dim3 grid(NBLOCKS);
    dim3 block(BLOCK);
    volrend_kernel<<<grid, block, 0, stream>>>(depth, density, feature, out);
}